// Round 1
// baseline (3305.276 us; speedup 1.0000x reference)
//
#include <hip/hip_runtime.h>
#include <math.h>

#define Bn 4
#define Sn 2048
#define En 1024
#define Hn 4
#define Dn 256
#define BSn (Bn*Sn)

__device__ __forceinline__ float elup1(float x) {
    // elu(x)+1 = x>0 ? x+1 : exp(x)
    return x > 0.0f ? x + 1.0f : __expf(x);
}

// ---------------- generic GEMM: C = A@W (+bias), all row-major --------------
// M,N multiples of 64; K multiple of 16. 64x64 tile, 256 threads, 4x4 micro.
__global__ __launch_bounds__(256) void gemm_bias_k(
    const float* __restrict__ A, const float* __restrict__ W,
    const float* __restrict__ bias, float* __restrict__ C,
    int M, int N, int K)
{
    __shared__ float As[16][64];
    __shared__ float Bs[16][64];
    const int tid = threadIdx.x;
    const int bm = blockIdx.y * 64;
    const int bn = blockIdx.x * 64;
    const int tr = tid >> 4;         // 0..15
    const int tc = tid & 15;         // 0..15
    const int ar = tid >> 2;         // 0..63  (A row in tile)
    const int ac = (tid & 3) << 2;   // 0,4,8,12 (A k-offset)
    const int wr = tid >> 4;         // 0..15  (W k-row)
    const int wc = (tid & 15) << 2;  // 0..60  (W col)
    float acc[4][4] = {};
    for (int k0 = 0; k0 < K; k0 += 16) {
        const float4 a4 = *(const float4*)(A + (size_t)(bm + ar) * K + (k0 + ac));
        As[ac + 0][ar] = a4.x;
        As[ac + 1][ar] = a4.y;
        As[ac + 2][ar] = a4.z;
        As[ac + 3][ar] = a4.w;
        const float4 w4 = *(const float4*)(W + (size_t)(k0 + wr) * N + (bn + wc));
        *(float4*)(&Bs[wr][wc]) = w4;
        __syncthreads();
        #pragma unroll
        for (int kk = 0; kk < 16; ++kk) {
            float a[4], bb[4];
            #pragma unroll
            for (int i = 0; i < 4; ++i) a[i] = As[kk][tr * 4 + i];
            #pragma unroll
            for (int j = 0; j < 4; ++j) bb[j] = Bs[kk][tc * 4 + j];
            #pragma unroll
            for (int i = 0; i < 4; ++i)
                #pragma unroll
                for (int j = 0; j < 4; ++j)
                    acc[i][j] += a[i] * bb[j];
        }
        __syncthreads();
    }
    #pragma unroll
    for (int i = 0; i < 4; ++i) {
        const int row = bm + tr * 4 + i;
        float4 r;
        r.x = acc[i][0]; r.y = acc[i][1]; r.z = acc[i][2]; r.w = acc[i][3];
        if (bias) {
            const float4 bv = *(const float4*)(bias + bn + tc * 4);
            r.x += bv.x; r.y += bv.y; r.z += bv.z; r.w += bv.w;
        }
        *(float4*)(C + (size_t)row * N + bn + tc * 4) = r;
    }
}

// --------- flash attention (causal) + compressive-memory read + gate --------
// block: 256 threads; Q-tile 32 rows, K-tile 16. Grid (S/32, H, B).
__global__ __launch_bounds__(256) void flash_gate_k(
    const float* __restrict__ Q, const float* __restrict__ Kg,
    const float* __restrict__ Vg, const float* __restrict__ memp,
    const float* __restrict__ zp, const float* __restrict__ betas,
    float* __restrict__ Cmb)
{
    __shared__ float Ks[16][257];   // padded: score phase conflict-free
    __shared__ float Vs[16][256];   // float4 lane-consecutive reads
    __shared__ float Ps[32][17];
    __shared__ float rowm[32], rowl[32], rowa[32], rowden[32];

    const int tid = threadIdx.x;
    const int qt = blockIdx.x;
    const int h  = blockIdx.y;
    const int b  = blockIdx.z;
    const int q0 = qt * 32;

    const float* Qb = Q  + ((size_t)b * Sn + q0) * En + h * Dn;  // row stride En
    const float* Kb = Kg + (size_t)b * Sn * En + h * Dn;
    const float* Vb = Vg + (size_t)b * Sn * En + h * Dn;
    const float* memh = memp + (size_t)h * Dn * Dn;
    const float* zh = zp + (size_t)h * Dn;

    const int c0 = (tid & 63) << 2;  // output col block (float4)
    const int rb = tid >> 6;         // row base: rows rb+4k, k=0..7

    // ---- A_mem denominators + per-row softmax state init
    {
        const int r  = tid >> 3;         // 0..31 (row)
        const int sl = (tid & 7) << 5;   // 32-elem d-slice
        const float* qr = Qb + (size_t)r * En;
        float part = 0.0f;
        #pragma unroll 8
        for (int d = 0; d < 32; ++d) part += elup1(qr[sl + d]) * zh[sl + d];
        part += __shfl_down(part, 4);
        part += __shfl_down(part, 2);
        part += __shfl_down(part, 1);
        if ((tid & 7) == 0) {
            rowden[r] = 1.0f / (part + 1e-6f);
            rowm[r] = -1e30f;
            rowl[r] = 0.0f;
        }
    }

    // ---- A_mem numerators: am[k][i] = sum_kk sigma_q[r][kk] * mem[kk][c0+i]
    float am[8][4] = {};
    for (int kk = 0; kk < Dn; ++kk) {
        const float4 m4 = *(const float4*)(memh + (size_t)kk * Dn + c0);
        #pragma unroll
        for (int k = 0; k < 8; ++k) {
            const float sq = elup1(Qb[(size_t)(rb + 4 * k) * En + kk]);
            am[k][0] += sq * m4.x;
            am[k][1] += sq * m4.y;
            am[k][2] += sq * m4.z;
            am[k][3] += sq * m4.w;
        }
    }
    __syncthreads();  // rowden/rowm/rowl visible

    float o[8][4] = {};

    const int sr = tid >> 3;        // score row 0..31
    const int sc = (tid & 7) << 1;  // score col base (2 cols/thread)
    const float* qsr = Qb + (size_t)sr * En;
    const int lr = tid >> 4;          // staging row 0..15
    const int ld = (tid & 15) << 4;   // staging col base (16 floats)

    const int ktend = 2 * qt + 1;     // last K-tile overlapping causal range
    for (int kt = 0; kt <= ktend; ++kt) {
        const int k0 = kt * 16;
        // stage K (padded, scalar stores) and V (float4) tiles
        const float* krow = Kb + (size_t)(k0 + lr) * En + ld;
        const float* vrow = Vb + (size_t)(k0 + lr) * En + ld;
        #pragma unroll
        for (int u = 0; u < 16; u += 4) {
            const float4 k4 = *(const float4*)(krow + u);
            Ks[lr][ld + u + 0] = k4.x;
            Ks[lr][ld + u + 1] = k4.y;
            Ks[lr][ld + u + 2] = k4.z;
            Ks[lr][ld + u + 3] = k4.w;
            const float4 v4 = *(const float4*)(vrow + u);
            *(float4*)(&Vs[lr][ld + u]) = v4;
        }
        __syncthreads();

        // scores: each thread 2 of 32x16
        float s0 = 0.0f, s1 = 0.0f;
        #pragma unroll 8
        for (int d = 0; d < Dn; ++d) {
            const float qv = qsr[d];     // global, L1-broadcast
            s0 += qv * Ks[sc + 0][d];
            s1 += qv * Ks[sc + 1][d];
        }
        const int qpos = q0 + sr;
        Ps[sr][sc + 0] = (k0 + sc + 0 <= qpos) ? s0 : -1e30f;
        Ps[sr][sc + 1] = (k0 + sc + 1 <= qpos) ? s1 : -1e30f;
        __syncthreads();

        // online softmax, one thread per row
        if (tid < 32) {
            const float mold = rowm[tid];
            float mx = mold;
            #pragma unroll
            for (int c = 0; c < 16; ++c) mx = fmaxf(mx, Ps[tid][c]);
            const float al = __expf(mold - mx);
            float ls = 0.0f;
            #pragma unroll
            for (int c = 0; c < 16; ++c) {
                const float p = __expf(Ps[tid][c] - mx);
                Ps[tid][c] = p;
                ls += p;
            }
            rowl[tid] = rowl[tid] * al + ls;
            rowm[tid] = mx;
            rowa[tid] = al;
        }
        __syncthreads();

        // rescale + PV accumulate
        #pragma unroll
        for (int k = 0; k < 8; ++k) {
            const float al = rowa[rb + 4 * k];  // broadcast
            o[k][0] *= al; o[k][1] *= al; o[k][2] *= al; o[k][3] *= al;
        }
        #pragma unroll 4
        for (int j = 0; j < 16; ++j) {
            const float4 v4 = *(const float4*)(&Vs[j][c0]);
            #pragma unroll
            for (int k = 0; k < 8; ++k) {
                const float p = Ps[rb + 4 * k][j];  // broadcast
                o[k][0] += p * v4.x;
                o[k][1] += p * v4.y;
                o[k][2] += p * v4.z;
                o[k][3] += p * v4.w;
            }
        }
        __syncthreads();
    }

    // epilogue: gate * A_mem + (1-gate) * attn, write [B,S,E] layout
    const float gate = 1.0f / (1.0f + __expf(-betas[h]));
    const float omg = 1.0f - gate;
    float* Cb = Cmb + ((size_t)b * Sn + q0) * En + h * Dn;
    #pragma unroll
    for (int k = 0; k < 8; ++k) {
        const int r = rb + 4 * k;
        const float rl = 1.0f / rowl[r];
        const float rd = rowden[r];
        float4 res;
        res.x = gate * am[k][0] * rd + omg * o[k][0] * rl;
        res.y = gate * am[k][1] * rd + omg * o[k][1] * rl;
        res.z = gate * am[k][2] * rd + omg * o[k][2] * rl;
        res.w = gate * am[k][3] * rd + omg * o[k][3] * rl;
        *(float4*)(Cb + (size_t)r * En + c0) = res;
    }
}

// --------- U = V - (sigma_k@mem)/(sigma_k.z+eps), in place on V -------------
__global__ __launch_bounds__(256) void delta_v_k(
    const float* __restrict__ Kg, float* __restrict__ Vg,
    const float* __restrict__ memp, const float* __restrict__ zp)
{
    __shared__ float SK[32][256];
    __shared__ float rden[32];
    const int tid = threadIdx.x;
    const int st = blockIdx.x;
    const int h  = blockIdx.y;
    const int b  = blockIdx.z;
    const int s0 = st * 32;
    const float* Kb = Kg + ((size_t)b * Sn + s0) * En + h * Dn;
    float* Vb = Vg + ((size_t)b * Sn + s0) * En + h * Dn;
    const float* memh = memp + (size_t)h * Dn * Dn;
    const float* zh = zp + (size_t)h * Dn;

    // stage sigma_k rows
    {
        const int lr = tid >> 3;
        const int ld = (tid & 7) << 5;
        const float* kr = Kb + (size_t)lr * En + ld;
        #pragma unroll
        for (int u = 0; u < 32; u += 4) {
            const float4 k4 = *(const float4*)(kr + u);
            float4 s4;
            s4.x = elup1(k4.x); s4.y = elup1(k4.y);
            s4.z = elup1(k4.z); s4.w = elup1(k4.w);
            *(float4*)(&SK[lr][ld + u]) = s4;
        }
    }
    __syncthreads();
    {
        const int r  = tid >> 3;
        const int sl = (tid & 7) << 5;
        float part = 0.0f;
        #pragma unroll 8
        for (int d = 0; d < 32; ++d) part += SK[r][sl + d] * zh[sl + d];
        part += __shfl_down(part, 4);
        part += __shfl_down(part, 2);
        part += __shfl_down(part, 1);
        if ((tid & 7) == 0) rden[r] = 1.0f / (part + 1e-6f);
    }
    __syncthreads();
    const int c0 = (tid & 63) << 2;
    const int rb = tid >> 6;
    float dl[8][4] = {};
    for (int kk = 0; kk < Dn; ++kk) {
        const float4 m4 = *(const float4*)(memh + (size_t)kk * Dn + c0);
        #pragma unroll
        for (int k = 0; k < 8; ++k) {
            const float sk = SK[rb + 4 * k][kk];  // broadcast
            dl[k][0] += sk * m4.x;
            dl[k][1] += sk * m4.y;
            dl[k][2] += sk * m4.z;
            dl[k][3] += sk * m4.w;
        }
    }
    #pragma unroll
    for (int k = 0; k < 8; ++k) {
        const int r = rb + 4 * k;
        const float rd = rden[r];
        float* vp = Vb + (size_t)r * En + c0;
        float4 v4 = *(const float4*)vp;
        v4.x -= dl[k][0] * rd;
        v4.y -= dl[k][1] * rd;
        v4.z -= dl[k][2] * rd;
        v4.w -= dl[k][3] * rd;
        *(float4*)vp = v4;
    }
}

// --------- mem_new[b,h] = mem[h] + sigma_k^T @ U  (256x256, K=2048) ---------
__global__ __launch_bounds__(256) void mem_update_k(
    const float* __restrict__ Kg, const float* __restrict__ U,
    const float* __restrict__ memp, float* __restrict__ mem_new)
{
    __shared__ float As[16][64];
    __shared__ float Bs[16][64];
    const int tid = threadIdx.x;
    const int bn = blockIdx.x * 64;   // e dim
    const int bm = blockIdx.y * 64;   // d dim
    const int bh = blockIdx.z;
    const int b = bh >> 2;
    const int h = bh & 3;
    const float* Kb = Kg + (size_t)b * Sn * En + h * Dn;
    const float* Ub = U  + (size_t)b * Sn * En + h * Dn;
    const int tr = tid >> 4, tc = tid & 15;
    const int lr = tid >> 4;
    const int lc = (tid & 15) << 2;
    float acc[4][4] = {};
    for (int s0 = 0; s0 < Sn; s0 += 16) {
        const float4 a4 = *(const float4*)(Kb + (size_t)(s0 + lr) * En + bm + lc);
        As[lr][lc + 0] = elup1(a4.x);
        As[lr][lc + 1] = elup1(a4.y);
        As[lr][lc + 2] = elup1(a4.z);
        As[lr][lc + 3] = elup1(a4.w);
        const float4 b4 = *(const float4*)(Ub + (size_t)(s0 + lr) * En + bn + lc);
        *(float4*)(&Bs[lr][lc]) = b4;
        __syncthreads();
        #pragma unroll
        for (int kk = 0; kk < 16; ++kk) {
            float a[4], bb[4];
            #pragma unroll
            for (int i = 0; i < 4; ++i) a[i] = As[kk][tr * 4 + i];
            #pragma unroll
            for (int j = 0; j < 4; ++j) bb[j] = Bs[kk][tc * 4 + j];
            #pragma unroll
            for (int i = 0; i < 4; ++i)
                #pragma unroll
                for (int j = 0; j < 4; ++j)
                    acc[i][j] += a[i] * bb[j];
        }
        __syncthreads();
    }
    const float* memh = memp + (size_t)h * Dn * Dn;
    float* mout = mem_new + (size_t)bh * Dn * Dn;
    #pragma unroll
    for (int i = 0; i < 4; ++i) {
        const int dm = bm + tr * 4 + i;
        const float4 m4 = *(const float4*)(memh + (size_t)dm * Dn + bn + tc * 4);
        float4 r;
        r.x = m4.x + acc[i][0];
        r.y = m4.y + acc[i][1];
        r.z = m4.z + acc[i][2];
        r.w = m4.w + acc[i][3];
        *(float4*)(mout + (size_t)dm * Dn + bn + tc * 4) = r;
    }
}

// --------- z_new = z + sum_s sigma_k ----------------------------------------
__global__ __launch_bounds__(256) void znew_init_k(
    const float* __restrict__ zp, float* __restrict__ z_new)
{
    const int bh = blockIdx.x;
    const int h = bh & 3;
    z_new[(size_t)bh * Dn + threadIdx.x] = zp[(size_t)h * Dn + threadIdx.x];
}

__global__ __launch_bounds__(256) void znew_acc_k(
    const float* __restrict__ Kg, float* __restrict__ z_new)
{
    const int bh = blockIdx.y;
    const int b = bh >> 2;
    const int h = bh & 3;
    const int s0 = blockIdx.x * 256;
    const float* Kb = Kg + ((size_t)b * Sn + s0) * En + h * Dn;
    float acc = 0.0f;
    for (int s = 0; s < 256; ++s) acc += elup1(Kb[(size_t)s * En + threadIdx.x]);
    atomicAdd(&z_new[(size_t)bh * Dn + threadIdx.x], acc);
}

extern "C" void kernel_launch(void* const* d_in, const int* in_sizes, int n_in,
                              void* d_out, int out_size, void* d_ws, size_t ws_size,
                              hipStream_t stream) {
    const float* hidden = (const float*)d_in[0];
    const float* Wq = (const float*)d_in[1];
    const float* Wk = (const float*)d_in[2];
    const float* Wv = (const float*)d_in[3];
    const float* Wo = (const float*)d_in[4];
    const float* bo = (const float*)d_in[5];
    const float* betas = (const float*)d_in[6];
    const float* memp = (const float*)d_in[7];
    const float* zp = (const float*)d_in[8];

    float* out = (float*)d_out;                                  // [B,S,E]
    float* mem_new = out + (size_t)Bn * Sn * En;                 // [B,H,D,D]
    float* z_new = mem_new + (size_t)Bn * Hn * Dn * Dn;          // [B,H,D]

    // workspace: Q,K,V,Cmb each B*S*E floats (total 134.2 MB)
    float* Q = (float*)d_ws;
    float* Kb = Q + (size_t)BSn * En;
    float* Vb = Kb + (size_t)BSn * En;
    float* Cmb = Vb + (size_t)BSn * En;

    const dim3 gg(En / 64, BSn / 64);  // (16,128)
    gemm_bias_k<<<gg, 256, 0, stream>>>(hidden, Wq, nullptr, Q, BSn, En, En);
    gemm_bias_k<<<gg, 256, 0, stream>>>(hidden, Wk, nullptr, Kb, BSn, En, En);
    gemm_bias_k<<<gg, 256, 0, stream>>>(hidden, Wv, nullptr, Vb, BSn, En, En);

    flash_gate_k<<<dim3(Sn / 32, Hn, Bn), 256, 0, stream>>>(
        Q, Kb, Vb, memp, zp, betas, Cmb);

    // V must be consumed by attention before being overwritten with U
    delta_v_k<<<dim3(Sn / 32, Hn, Bn), 256, 0, stream>>>(Kb, Vb, memp, zp);

    mem_update_k<<<dim3(Dn / 64, Dn / 64, Bn * Hn), 256, 0, stream>>>(
        Kb, Vb, memp, mem_new);

    znew_init_k<<<Bn * Hn, 256, 0, stream>>>(zp, z_new);
    znew_acc_k<<<dim3(Sn / 256, Bn * Hn), 256, 0, stream>>>(Kb, z_new);

    gemm_bias_k<<<gg, 256, 0, stream>>>(Cmb, Wo, bo, out, BSn, En, En);
}

// Round 2
// 795.211 us; speedup vs baseline: 4.1565x; 4.1565x over previous
//
#include <hip/hip_runtime.h>
#include <math.h>

#define Bn 4
#define Sn 2048
#define En 1024
#define Hn 4
#define Dn 256

typedef _Float16 half8 __attribute__((ext_vector_type(8)));
typedef _Float16 half4v __attribute__((ext_vector_type(4)));
typedef float floatx4 __attribute__((ext_vector_type(4)));

#define MFMA16(a, b, c) __builtin_amdgcn_mfma_f32_16x16x32_f16((a), (b), (c), 0, 0, 0)

__device__ __forceinline__ float elup1(float x) {
    return x > 0.0f ? x + 1.0f : __expf(x);
}

// ---------- fp32 -> fp16 elementwise convert (hidden) -----------------------
__global__ void cvt_h_k(const float* __restrict__ src, _Float16* __restrict__ dst, int n4) {
    int idx = blockIdx.x * 256 + threadIdx.x;
    const int stride = gridDim.x * 256;
    for (; idx < n4; idx += stride) {
        float4 v = ((const float4*)src)[idx];
        half4v o;
        o[0] = (_Float16)v.x; o[1] = (_Float16)v.y;
        o[2] = (_Float16)v.z; o[3] = (_Float16)v.w;
        ((half4v*)dst)[idx] = o;
    }
}

// ---------- fp32 [R][C] -> fp16 transposed [C][R], batched ------------------
__global__ __launch_bounds__(256) void trans_f32f16_k(
    const float* __restrict__ src, _Float16* __restrict__ dst, int R, int C) {
    __shared__ float T[64][65];
    const int tid = threadIdx.x;
    const int c0 = blockIdx.x * 64, r0 = blockIdx.y * 64;
    src += (size_t)blockIdx.z * R * C;
    dst += (size_t)blockIdx.z * R * C;
    {
        const int tr = tid >> 2, tc = (tid & 3) * 16;
        const float* s = src + (size_t)(r0 + tr) * C + c0 + tc;
        #pragma unroll
        for (int i = 0; i < 4; ++i) {
            float4 v = *(const float4*)(s + i * 4);
            T[tr][tc + i * 4 + 0] = v.x;
            T[tr][tc + i * 4 + 1] = v.y;
            T[tr][tc + i * 4 + 2] = v.z;
            T[tr][tc + i * 4 + 3] = v.w;
        }
    }
    __syncthreads();
    {
        const int cr = tid >> 2, rc = (tid & 3) * 16;
        half8 h0, h1;
        #pragma unroll
        for (int i = 0; i < 8; ++i) h0[i] = (_Float16)T[rc + i][cr];
        #pragma unroll
        for (int i = 0; i < 8; ++i) h1[i] = (_Float16)T[rc + 8 + i][cr];
        _Float16* d = dst + (size_t)(c0 + cr) * R + r0 + rc;
        *(half8*)d = h0;
        *(half8*)(d + 8) = h1;
    }
}

// ---------- V fp16 [B*S][E] -> Vt fp16 [B*H][D][S] --------------------------
__global__ __launch_bounds__(256) void trans_h16_k(
    const _Float16* __restrict__ Vh, _Float16* __restrict__ Vtg) {
    __shared__ __align__(16) unsigned short T[64 * 72];
    const int tid = threadIdx.x;
    const int s0 = blockIdx.x * 64;
    const int e0 = blockIdx.y * 64;
    const int b = blockIdx.z;
    const int h = e0 >> 8, d0 = e0 & 255;
    {
        const int tr = tid >> 2, tc = (tid & 3) * 16;
        const _Float16* s = Vh + (size_t)(b * Sn + s0 + tr) * En + e0 + tc;
        _Float16* d = (_Float16*)T + tr * 72 + tc;
        *(half8*)d = *(const half8*)s;
        *(half8*)(d + 8) = *(const half8*)(s + 8);
    }
    __syncthreads();
    {
        const int dr = tid >> 2, sc = (tid & 3) * 16;
        const _Float16* Tp = (const _Float16*)T;
        half8 h0, h1;
        #pragma unroll
        for (int i = 0; i < 8; ++i) h0[i] = Tp[(sc + i) * 72 + dr];
        #pragma unroll
        for (int i = 0; i < 8; ++i) h1[i] = Tp[(sc + 8 + i) * 72 + dr];
        _Float16* d = Vtg + (size_t)((b * 4 + h) * 256 + d0 + dr) * (size_t)Sn + s0 + sc;
        *(half8*)d = h0;
        *(half8*)(d + 8) = h1;
    }
}

// ---------- fp16 GEMM: C[M][1024] = A[M][1024] @ Bt[n][k]^T (+bias) ---------
// 128x128 tile, BK=32, 4 waves, 16x16x32 MFMA. C16 != null -> fp16 out;
// else fp32 out + bias.
__global__ __launch_bounds__(256) void gemm16_k(
    const _Float16* __restrict__ A, const _Float16* __restrict__ Bt,
    _Float16* __restrict__ C16, float* __restrict__ C32,
    const float* __restrict__ bias) {
    __shared__ __align__(16) unsigned short Ah[128 * 40];
    __shared__ __align__(16) unsigned short Bh[128 * 40];
    const int tid = threadIdx.x;
    const int lane = tid & 63, w = tid >> 6, quad = lane >> 4, l15 = lane & 15;
    const int bm = blockIdx.y * 128, bn = blockIdx.x * 128;
    floatx4 acc[2][8];
    #pragma unroll
    for (int mt = 0; mt < 2; ++mt)
        #pragma unroll
        for (int nt = 0; nt < 8; ++nt) acc[mt][nt] = (floatx4){0.f, 0.f, 0.f, 0.f};

    const int srow = tid >> 1, skoff = (tid & 1) * 16;
    const _Float16* as = A + (size_t)(bm + srow) * 1024 + skoff;
    const _Float16* bs = Bt + (size_t)(bn + srow) * 1024 + skoff;
    _Float16* ad = (_Float16*)Ah + srow * 40 + skoff;
    _Float16* bd = (_Float16*)Bh + srow * 40 + skoff;

    for (int k0 = 0; k0 < 1024; k0 += 32) {
        if (k0) __syncthreads();
        *(half8*)ad = *(const half8*)(as + k0);
        *(half8*)(ad + 8) = *(const half8*)(as + k0 + 8);
        *(half8*)bd = *(const half8*)(bs + k0);
        *(half8*)(bd + 8) = *(const half8*)(bs + k0 + 8);
        __syncthreads();
        half8 af0 = *(const half8*)((const _Float16*)Ah + (w * 32 + l15) * 40 + quad * 8);
        half8 af1 = *(const half8*)((const _Float16*)Ah + (w * 32 + 16 + l15) * 40 + quad * 8);
        #pragma unroll
        for (int nt = 0; nt < 8; ++nt) {
            half8 bf = *(const half8*)((const _Float16*)Bh + (nt * 16 + l15) * 40 + quad * 8);
            acc[0][nt] = MFMA16(af0, bf, acc[0][nt]);
            acc[1][nt] = MFMA16(af1, bf, acc[1][nt]);
        }
    }
    #pragma unroll
    for (int mt = 0; mt < 2; ++mt)
        #pragma unroll
        for (int nt = 0; nt < 8; ++nt)
            #pragma unroll
            for (int r = 0; r < 4; ++r) {
                const int row = bm + w * 32 + mt * 16 + quad * 4 + r;
                const int col = bn + nt * 16 + l15;
                if (C16)
                    C16[(size_t)row * 1024 + col] = (_Float16)acc[mt][nt][r];
                else
                    C32[(size_t)row * 1024 + col] = acc[mt][nt][r] + bias[col];
            }
}

// ---------- fused flash attention + compressive memory read + gate ----------
// grid (32, 16): qt = 31-bx (reversed for load balance), bh = by.
// Q-tile 64 rows (16/wave, A-frags in registers), K-tile 32.
__global__ __launch_bounds__(256) void flash_gate_k(
    const _Float16* __restrict__ Qh, const _Float16* __restrict__ Khg,
    const _Float16* __restrict__ Vtg, const _Float16* __restrict__ memT,
    const float* __restrict__ zp, const float* __restrict__ betas,
    _Float16* __restrict__ Cmb) {
    __shared__ __align__(16) unsigned short Ksh[32 * 264];
    __shared__ __align__(16) unsigned short Vt[256 * 40];
    __shared__ __align__(16) unsigned short Pb[4 * 16 * 40];

    const int tid = threadIdx.x;
    const int lane = tid & 63;
    const int w = tid >> 6;
    const int quad = lane >> 4;
    const int l15 = lane & 15;
    const int qt = 31 - blockIdx.x;
    const int bh = blockIdx.y;
    const int b = bh >> 2;
    const int h = bh & 3;
    const int q0 = qt * 64;

    // ---- Q fragments (A-layout: m=lane&15, k=quad*8+j) + sigma_q + denom
    const _Float16* Qrow = Qh + (size_t)(b * Sn + q0 + w * 16 + l15) * En + h * Dn;
    half8 qf[8], sf[8];
    float denp = 0.0f;
    #pragma unroll
    for (int kc = 0; kc < 8; ++kc) {
        half8 qv = *(const half8*)(Qrow + kc * 32 + quad * 8);
        qf[kc] = qv;
        const float* zb = zp + h * Dn + kc * 32 + quad * 8;
        float4 z0 = *(const float4*)zb;
        float4 z1 = *(const float4*)(zb + 4);
        float zz[8] = {z0.x, z0.y, z0.z, z0.w, z1.x, z1.y, z1.z, z1.w};
        half8 sv;
        #pragma unroll
        for (int j = 0; j < 8; ++j) {
            float s = elup1((float)qv[j]);
            sv[j] = (_Float16)s;
            denp += s * zz[j];
        }
        sf[kc] = sv;
    }
    denp += __shfl_xor(denp, 16);
    denp += __shfl_xor(denp, 32);
    const float deninv = 1.0f / (denp + 1e-6f);
    float den4[4];
    #pragma unroll
    for (int r = 0; r < 4; ++r) den4[r] = __shfl(deninv, quad * 4 + r);

    // ---- A_mem = sigma_q @ mem via MFMA (mem transposed chunks in LDS)
    floatx4 acc[16];
    #pragma unroll
    for (int nt = 0; nt < 16; ++nt) acc[nt] = (floatx4){0.f, 0.f, 0.f, 0.f};

    const _Float16* memh = memT + (size_t)h * 256 * 256;
    for (int dc = 0; dc < 8; ++dc) {
        __syncthreads();
        {
            const _Float16* src = memh + (size_t)tid * 256 + dc * 32;
            _Float16* dst = (_Float16*)Vt + tid * 40;
            #pragma unroll
            for (int u = 0; u < 4; ++u) *(half8*)(dst + u * 8) = *(const half8*)(src + u * 8);
        }
        __syncthreads();
        #pragma unroll
        for (int nt = 0; nt < 16; ++nt) {
            half8 bm = *(const half8*)((const _Float16*)Vt + (nt * 16 + l15) * 40 + quad * 8);
            acc[nt] = MFMA16(sf[dc], bm, acc[nt]);
        }
    }

    const float gate = 1.0f / (1.0f + __expf(-betas[h]));
    const float omg = 1.0f - gate;
    _Float16* Cb = Cmb + (size_t)(b * Sn + q0 + w * 16) * En + h * Dn;
    #pragma unroll
    for (int nt = 0; nt < 16; ++nt)
        #pragma unroll
        for (int r = 0; r < 4; ++r) {
            Cb[(size_t)(quad * 4 + r) * En + nt * 16 + l15] =
                (_Float16)(gate * acc[nt][r] * den4[r]);
            acc[nt][r] = 0.0f;
        }

    // ---- causal flash loop, K-tile = 32
    float mold[4] = {-1e30f, -1e30f, -1e30f, -1e30f};
    float lsum[4] = {0.f, 0.f, 0.f, 0.f};
    float alpha[4];
    const _Float16* Kbase = Khg + (size_t)(b * Sn) * En + h * Dn;
    const _Float16* Vtb = Vtg + (size_t)bh * 256 * (size_t)Sn;
    const int ktend = 2 * qt + 1;
    for (int kt = 0; kt <= ktend; ++kt) {
        const int k0 = kt * 32;
        __syncthreads();
        {
            const int r = tid >> 3, doff = (tid & 7) * 32;
            const _Float16* src = Kbase + (size_t)(k0 + r) * En + doff;
            _Float16* dst = (_Float16*)Ksh + r * 264 + doff;
            #pragma unroll
            for (int u = 0; u < 4; ++u) *(half8*)(dst + u * 8) = *(const half8*)(src + u * 8);
        }
        {
            const _Float16* src = Vtb + (size_t)tid * Sn + k0;
            _Float16* dst = (_Float16*)Vt + tid * 40;
            #pragma unroll
            for (int u = 0; u < 4; ++u) *(half8*)(dst + u * 8) = *(const half8*)(src + u * 8);
        }
        __syncthreads();

        // scores: S[2] frags of 16x16, K-dim = 256 via 8 chunks
        floatx4 S[2];
        S[0] = (floatx4){0.f, 0.f, 0.f, 0.f};
        S[1] = (floatx4){0.f, 0.f, 0.f, 0.f};
        #pragma unroll
        for (int kc = 0; kc < 8; ++kc) {
            half8 kf0 = *(const half8*)((const _Float16*)Ksh + l15 * 264 + kc * 32 + quad * 8);
            half8 kf1 = *(const half8*)((const _Float16*)Ksh + (16 + l15) * 264 + kc * 32 + quad * 8);
            S[0] = MFMA16(qf[kc], kf0, S[0]);
            S[1] = MFMA16(qf[kc], kf1, S[1]);
        }
        if (kt >= 2 * qt) {  // diagonal tiles: causal mask
            #pragma unroll
            for (int nt = 0; nt < 2; ++nt)
                #pragma unroll
                for (int r = 0; r < 4; ++r) {
                    const int kg = k0 + nt * 16 + l15;
                    const int qg = q0 + w * 16 + quad * 4 + r;
                    if (kg > qg) S[nt][r] = -1e30f;
                }
        }
        // online softmax (rows live in (quad, reg); reduce over 16 lanes)
        #pragma unroll
        for (int r = 0; r < 4; ++r) {
            float mx = fmaxf(S[0][r], S[1][r]);
            mx = fmaxf(mx, __shfl_xor(mx, 1));
            mx = fmaxf(mx, __shfl_xor(mx, 2));
            mx = fmaxf(mx, __shfl_xor(mx, 4));
            mx = fmaxf(mx, __shfl_xor(mx, 8));
            const float mnew = fmaxf(mold[r], mx);
            alpha[r] = __expf(mold[r] - mnew);
            mold[r] = mnew;
            const float p0 = __expf(S[0][r] - mnew);
            const float p1 = __expf(S[1][r] - mnew);
            float ps = p0 + p1;
            ps += __shfl_xor(ps, 1);
            ps += __shfl_xor(ps, 2);
            ps += __shfl_xor(ps, 4);
            ps += __shfl_xor(ps, 8);
            lsum[r] = lsum[r] * alpha[r] + ps;
            _Float16* pr = (_Float16*)Pb + (w * 16 + quad * 4 + r) * 40;
            pr[l15] = (_Float16)p0;
            pr[16 + l15] = (_Float16)p1;
        }
        #pragma unroll
        for (int nt = 0; nt < 16; ++nt)
            #pragma unroll
            for (int r = 0; r < 4; ++r) acc[nt][r] *= alpha[r];
        __syncthreads();  // P C-layout -> A-layout round trip
        half8 pf = *(const half8*)((const _Float16*)Pb + (w * 16 + l15) * 40 + quad * 8);
        #pragma unroll
        for (int nt = 0; nt < 16; ++nt) {
            half8 vf = *(const half8*)((const _Float16*)Vt + (nt * 16 + l15) * 40 + quad * 8);
            acc[nt] = MFMA16(pf, vf, acc[nt]);
        }
    }

    // ---- epilogue: Cmb += (1-gate) * O / l
    #pragma unroll
    for (int r = 0; r < 4; ++r) alpha[r] = omg / lsum[r];
    #pragma unroll
    for (int nt = 0; nt < 16; ++nt)
        #pragma unroll
        for (int r = 0; r < 4; ++r) {
            const size_t idx = (size_t)(quad * 4 + r) * En + nt * 16 + l15;
            const float prev = (float)Cb[idx];
            Cb[idx] = (_Float16)(prev + acc[nt][r] * alpha[r]);
        }
}

// ---------- U = V - (sigma_k@mem)/(sigma_k.z+eps), in place on V (fp16) -----
__global__ __launch_bounds__(256) void delta_v_k(
    const _Float16* __restrict__ Kg, _Float16* __restrict__ Vg,
    const float* __restrict__ memp, const float* __restrict__ zp) {
    __shared__ float SK[32][256];
    __shared__ float rden[32];
    const int tid = threadIdx.x;
    const int st = blockIdx.x;
    const int h = blockIdx.y;
    const int b = blockIdx.z;
    const int s0 = st * 32;
    const _Float16* Kb = Kg + (size_t)(b * Sn + s0) * En + h * Dn;
    _Float16* Vb = Vg + (size_t)(b * Sn + s0) * En + h * Dn;
    const float* memh = memp + (size_t)h * Dn * Dn;
    const float* zh = zp + (size_t)h * Dn;

    {
        const int lr = tid >> 3, ld = (tid & 7) * 32;
        const _Float16* kr = Kb + (size_t)lr * En + ld;
        #pragma unroll
        for (int u = 0; u < 4; ++u) {
            half8 k8 = *(const half8*)(kr + u * 8);
            #pragma unroll
            for (int j = 0; j < 8; ++j) SK[lr][ld + u * 8 + j] = elup1((float)k8[j]);
        }
    }
    __syncthreads();
    {
        const int r = tid >> 3;
        const int sl = (tid & 7) << 5;
        float part = 0.0f;
        #pragma unroll 8
        for (int d = 0; d < 32; ++d) part += SK[r][sl + d] * zh[sl + d];
        part += __shfl_down(part, 4);
        part += __shfl_down(part, 2);
        part += __shfl_down(part, 1);
        if ((tid & 7) == 0) rden[r] = 1.0f / (part + 1e-6f);
    }
    __syncthreads();
    const int c0 = (tid & 63) << 2;
    const int rb = tid >> 6;
    float dl[8][4] = {};
    for (int kk = 0; kk < Dn; ++kk) {
        const float4 m4 = *(const float4*)(memh + (size_t)kk * Dn + c0);
        #pragma unroll
        for (int k = 0; k < 8; ++k) {
            const float sk = SK[rb + 4 * k][kk];
            dl[k][0] += sk * m4.x;
            dl[k][1] += sk * m4.y;
            dl[k][2] += sk * m4.z;
            dl[k][3] += sk * m4.w;
        }
    }
    #pragma unroll
    for (int k = 0; k < 8; ++k) {
        const int r = rb + 4 * k;
        const float rd = rden[r];
        _Float16* vp = Vb + (size_t)r * En + c0;
        half4v v4 = *(half4v*)vp;
        #pragma unroll
        for (int j = 0; j < 4; ++j) v4[j] = (_Float16)((float)v4[j] - dl[k][j] * rd);
        *(half4v*)vp = v4;
    }
}

// ---------- mem_new[b,h] = mem[h] + sigma_k^T @ U  (fp32 vector) ------------
__global__ __launch_bounds__(256) void mem_update_k(
    const _Float16* __restrict__ Kg, const _Float16* __restrict__ U,
    const float* __restrict__ memp, float* __restrict__ mem_new) {
    __shared__ float As[16][64];
    __shared__ float Bs[16][64];
    const int tid = threadIdx.x;
    const int bn = blockIdx.x * 64;
    const int bm = blockIdx.y * 64;
    const int bh = blockIdx.z;
    const int b = bh >> 2;
    const int h = bh & 3;
    const _Float16* Kb = Kg + (size_t)b * Sn * En + h * Dn;
    const _Float16* Ub = U + (size_t)b * Sn * En + h * Dn;
    const int tr = tid >> 4, tc = tid & 15;
    const int lr = tid >> 4;
    const int lc = (tid & 15) << 2;
    float acc[4][4] = {};
    for (int s0 = 0; s0 < Sn; s0 += 16) {
        half4v a4 = *(const half4v*)(Kb + (size_t)(s0 + lr) * En + bm + lc);
        As[lr][lc + 0] = elup1((float)a4[0]);
        As[lr][lc + 1] = elup1((float)a4[1]);
        As[lr][lc + 2] = elup1((float)a4[2]);
        As[lr][lc + 3] = elup1((float)a4[3]);
        half4v b4 = *(const half4v*)(Ub + (size_t)(s0 + lr) * En + bn + lc);
        Bs[lr][lc + 0] = (float)b4[0];
        Bs[lr][lc + 1] = (float)b4[1];
        Bs[lr][lc + 2] = (float)b4[2];
        Bs[lr][lc + 3] = (float)b4[3];
        __syncthreads();
        #pragma unroll
        for (int kk = 0; kk < 16; ++kk) {
            float a[4], bb[4];
            #pragma unroll
            for (int i = 0; i < 4; ++i) a[i] = As[kk][tr * 4 + i];
            #pragma unroll
            for (int j = 0; j < 4; ++j) bb[j] = Bs[kk][tc * 4 + j];
            #pragma unroll
            for (int i = 0; i < 4; ++i)
                #pragma unroll
                for (int j = 0; j < 4; ++j)
                    acc[i][j] += a[i] * bb[j];
        }
        __syncthreads();
    }
    const float* memh = memp + (size_t)h * Dn * Dn;
    float* mout = mem_new + (size_t)bh * Dn * Dn;
    #pragma unroll
    for (int i = 0; i < 4; ++i) {
        const int dm = bm + tr * 4 + i;
        const float4 m4 = *(const float4*)(memh + (size_t)dm * Dn + bn + tc * 4);
        float4 r;
        r.x = m4.x + acc[i][0];
        r.y = m4.y + acc[i][1];
        r.z = m4.z + acc[i][2];
        r.w = m4.w + acc[i][3];
        *(float4*)(mout + (size_t)dm * Dn + bn + tc * 4) = r;
    }
}

// ---------- z_new = z + sum_s sigma_k ----------------------------------------
__global__ __launch_bounds__(256) void znew_init_k(
    const float* __restrict__ zp, float* __restrict__ z_new) {
    const int bh = blockIdx.x;
    const int h = bh & 3;
    z_new[(size_t)bh * Dn + threadIdx.x] = zp[(size_t)h * Dn + threadIdx.x];
}

__global__ __launch_bounds__(256) void znew_acc_k(
    const _Float16* __restrict__ Kg, float* __restrict__ z_new) {
    const int bh = blockIdx.y;
    const int b = bh >> 2;
    const int h = bh & 3;
    const int s0 = blockIdx.x * 256;
    const _Float16* Kb = Kg + (size_t)(b * Sn + s0) * En + h * Dn;
    float acc = 0.0f;
    for (int s = 0; s < 256; ++s) acc += elup1((float)Kb[(size_t)s * En + threadIdx.x]);
    atomicAdd(&z_new[(size_t)bh * Dn + threadIdx.x], acc);
}

extern "C" void kernel_launch(void* const* d_in, const int* in_sizes, int n_in,
                              void* d_out, int out_size, void* d_ws, size_t ws_size,
                              hipStream_t stream) {
    const float* hidden = (const float*)d_in[0];
    const float* Wq = (const float*)d_in[1];
    const float* Wk = (const float*)d_in[2];
    const float* Wv = (const float*)d_in[3];
    const float* Wo = (const float*)d_in[4];
    const float* bo = (const float*)d_in[5];
    const float* betas = (const float*)d_in[6];
    const float* memp = (const float*)d_in[7];
    const float* zp = (const float*)d_in[8];

    float* out = (float*)d_out;                           // [B,S,E]
    float* mem_new = out + (size_t)Bn * Sn * En;          // [B,H,D,D]
    float* z_new = mem_new + (size_t)Bn * Hn * Dn * Dn;   // [B,H,D]

    // workspace (fp16): 6 big buffers + 4 transposed weights + memT = ~110 MB
    _Float16* p = (_Float16*)d_ws;
    const size_t BSE = (size_t)Bn * Sn * En;
    _Float16* hh   = p; p += BSE;
    _Float16* Qh   = p; p += BSE;
    _Float16* Kh   = p; p += BSE;
    _Float16* Vh   = p; p += BSE;
    _Float16* Vtg  = p; p += BSE;
    _Float16* Cmb  = p; p += BSE;
    _Float16* WqT  = p; p += (size_t)En * En;
    _Float16* WkT  = p; p += (size_t)En * En;
    _Float16* WvT  = p; p += (size_t)En * En;
    _Float16* WoT  = p; p += (size_t)En * En;
    _Float16* memT = p; p += (size_t)Hn * Dn * Dn;

    cvt_h_k<<<2048, 256, 0, stream>>>(hidden, hh, (int)(BSE / 4));
    trans_f32f16_k<<<dim3(16, 16, 1), 256, 0, stream>>>(Wq, WqT, En, En);
    trans_f32f16_k<<<dim3(16, 16, 1), 256, 0, stream>>>(Wk, WkT, En, En);
    trans_f32f16_k<<<dim3(16, 16, 1), 256, 0, stream>>>(Wv, WvT, En, En);
    trans_f32f16_k<<<dim3(16, 16, 1), 256, 0, stream>>>(Wo, WoT, En, En);
    trans_f32f16_k<<<dim3(4, 4, 4), 256, 0, stream>>>(memp, memT, Dn, Dn);

    gemm16_k<<<dim3(8, 64), 256, 0, stream>>>(hh, WqT, Qh, nullptr, nullptr);
    gemm16_k<<<dim3(8, 64), 256, 0, stream>>>(hh, WkT, Kh, nullptr, nullptr);
    gemm16_k<<<dim3(8, 64), 256, 0, stream>>>(hh, WvT, Vh, nullptr, nullptr);

    trans_h16_k<<<dim3(32, 16, 4), 256, 0, stream>>>(Vh, Vtg);

    flash_gate_k<<<dim3(32, 16), 256, 0, stream>>>(Qh, Kh, Vtg, memT, zp, betas, Cmb);

    delta_v_k<<<dim3(64, 4, 4), 256, 0, stream>>>(Kh, Vh, memp, zp);
    mem_update_k<<<dim3(4, 4, 16), 256, 0, stream>>>(Kh, Vh, memp, mem_new);

    znew_init_k<<<16, 256, 0, stream>>>(zp, z_new);
    znew_acc_k<<<dim3(8, 16), 256, 0, stream>>>(Kh, z_new);

    gemm16_k<<<dim3(8, 64), 256, 0, stream>>>(Cmb, WoT, nullptr, out, bo);
}

// Round 3
// 651.477 us; speedup vs baseline: 5.0735x; 1.2206x over previous
//
#include <hip/hip_runtime.h>
#include <math.h>

#define Bn 4
#define Sn 2048
#define En 1024
#define Hn 4
#define Dn 256

typedef _Float16 half8 __attribute__((ext_vector_type(8)));
typedef _Float16 half4v __attribute__((ext_vector_type(4)));
typedef float floatx4 __attribute__((ext_vector_type(4)));

#define MFMA16(a, b, c) __builtin_amdgcn_mfma_f32_16x16x32_f16((a), (b), (c), 0, 0, 0)

__device__ __forceinline__ float elup1(float x) {
    return x > 0.0f ? x + 1.0f : __expf(x);
}

// ---------- fp32 [R][C] -> fp16 transposed [C][R], batched ------------------
__global__ __launch_bounds__(256) void trans_f32f16_k(
    const float* __restrict__ src, _Float16* __restrict__ dst, int R, int C) {
    __shared__ float T[64][65];
    const int tid = threadIdx.x;
    const int c0 = blockIdx.x * 64, r0 = blockIdx.y * 64;
    src += (size_t)blockIdx.z * R * C;
    dst += (size_t)blockIdx.z * R * C;
    {
        const int tr = tid >> 2, tc = (tid & 3) * 16;
        const float* s = src + (size_t)(r0 + tr) * C + c0 + tc;
        #pragma unroll
        for (int i = 0; i < 4; ++i) {
            float4 v = *(const float4*)(s + i * 4);
            T[tr][tc + i * 4 + 0] = v.x;
            T[tr][tc + i * 4 + 1] = v.y;
            T[tr][tc + i * 4 + 2] = v.z;
            T[tr][tc + i * 4 + 3] = v.w;
        }
    }
    __syncthreads();
    {
        const int cr = tid >> 2, rc = (tid & 3) * 16;
        half8 h0, h1;
        #pragma unroll
        for (int i = 0; i < 8; ++i) h0[i] = (_Float16)T[rc + i][cr];
        #pragma unroll
        for (int i = 0; i < 8; ++i) h1[i] = (_Float16)T[rc + 8 + i][cr];
        _Float16* d = dst + (size_t)(c0 + cr) * R + r0 + rc;
        *(half8*)d = h0;
        *(half8*)(d + 8) = h1;
    }
}

// ---------- V fp16 [B*S][E] -> Vt fp16 [B*H][D][S] --------------------------
__global__ __launch_bounds__(256) void trans_h16_k(
    const _Float16* __restrict__ Vh, _Float16* __restrict__ Vtg) {
    __shared__ __align__(16) unsigned short T[64 * 72];
    const int tid = threadIdx.x;
    const int s0 = blockIdx.x * 64;
    const int e0 = blockIdx.y * 64;
    const int b = blockIdx.z;
    const int h = e0 >> 8, d0 = e0 & 255;
    {
        const int tr = tid >> 2, tc = (tid & 3) * 16;
        const _Float16* s = Vh + (size_t)(b * Sn + s0 + tr) * En + e0 + tc;
        _Float16* d = (_Float16*)T + tr * 72 + tc;
        *(half8*)d = *(const half8*)s;
        *(half8*)(d + 8) = *(const half8*)(s + 8);
    }
    __syncthreads();
    {
        const int dr = tid >> 2, sc = (tid & 3) * 16;
        const _Float16* Tp = (const _Float16*)T;
        half8 h0, h1;
        #pragma unroll
        for (int i = 0; i < 8; ++i) h0[i] = Tp[(sc + i) * 72 + dr];
        #pragma unroll
        for (int i = 0; i < 8; ++i) h1[i] = Tp[(sc + 8 + i) * 72 + dr];
        _Float16* d = Vtg + (size_t)((b * 4 + h) * 256 + d0 + dr) * (size_t)Sn + s0 + sc;
        *(half8*)d = h0;
        *(half8*)(d + 8) = h1;
    }
}

// ---------- GEMM: C[M][1024] = A[M][1024] @ Bt[n][k]^T (+bias) --------------
// A32: A is fp32 (converted in staging). 128x128 tile, BK=32, 4 waves.
template <bool A32>
__global__ __launch_bounds__(256) void gemm16_k(
    const void* __restrict__ Ap, const _Float16* __restrict__ Bt,
    _Float16* __restrict__ C16, float* __restrict__ C32,
    const float* __restrict__ bias) {
    __shared__ __align__(16) unsigned short Ah[128 * 40];
    __shared__ __align__(16) unsigned short Bh[128 * 40];
    const int tid = threadIdx.x;
    const int lane = tid & 63, w = tid >> 6, quad = lane >> 4, l15 = lane & 15;
    const int bm = blockIdx.y * 128, bn = blockIdx.x * 128;
    floatx4 acc[2][8];
    #pragma unroll
    for (int mt = 0; mt < 2; ++mt)
        #pragma unroll
        for (int nt = 0; nt < 8; ++nt) acc[mt][nt] = (floatx4){0.f, 0.f, 0.f, 0.f};

    const int srow = tid >> 1, skoff = (tid & 1) * 16;
    const _Float16* bs = Bt + (size_t)(bn + srow) * 1024 + skoff;
    _Float16* ad = (_Float16*)Ah + srow * 40 + skoff;
    _Float16* bd = (_Float16*)Bh + srow * 40 + skoff;

    for (int k0 = 0; k0 < 1024; k0 += 32) {
        if (k0) __syncthreads();
        if constexpr (A32) {
            const float* as = (const float*)Ap + (size_t)(bm + srow) * 1024 + skoff + k0;
            half8 h0, h1;
            #pragma unroll
            for (int i = 0; i < 2; ++i) {
                float4 f0 = *(const float4*)(as + i * 8);
                float4 f1 = *(const float4*)(as + i * 8 + 4);
                half8* hp = i ? &h1 : &h0;
                (*hp)[0] = (_Float16)f0.x; (*hp)[1] = (_Float16)f0.y;
                (*hp)[2] = (_Float16)f0.z; (*hp)[3] = (_Float16)f0.w;
                (*hp)[4] = (_Float16)f1.x; (*hp)[5] = (_Float16)f1.y;
                (*hp)[6] = (_Float16)f1.z; (*hp)[7] = (_Float16)f1.w;
            }
            *(half8*)ad = h0;
            *(half8*)(ad + 8) = h1;
        } else {
            const _Float16* as = (const _Float16*)Ap + (size_t)(bm + srow) * 1024 + skoff + k0;
            *(half8*)ad = *(const half8*)as;
            *(half8*)(ad + 8) = *(const half8*)(as + 8);
        }
        *(half8*)bd = *(const half8*)(bs + k0);
        *(half8*)(bd + 8) = *(const half8*)(bs + k0 + 8);
        __syncthreads();
        half8 af0 = *(const half8*)((const _Float16*)Ah + (w * 32 + l15) * 40 + quad * 8);
        half8 af1 = *(const half8*)((const _Float16*)Ah + (w * 32 + 16 + l15) * 40 + quad * 8);
        #pragma unroll
        for (int nt = 0; nt < 8; ++nt) {
            half8 bf = *(const half8*)((const _Float16*)Bh + (nt * 16 + l15) * 40 + quad * 8);
            acc[0][nt] = MFMA16(af0, bf, acc[0][nt]);
            acc[1][nt] = MFMA16(af1, bf, acc[1][nt]);
        }
    }
    #pragma unroll
    for (int mt = 0; mt < 2; ++mt)
        #pragma unroll
        for (int nt = 0; nt < 8; ++nt)
            #pragma unroll
            for (int r = 0; r < 4; ++r) {
                const int row = bm + w * 32 + mt * 16 + quad * 4 + r;
                const int col = bn + nt * 16 + l15;
                if (C16)
                    C16[(size_t)row * 1024 + col] = (_Float16)acc[mt][nt][r];
                else
                    C32[(size_t)row * 1024 + col] = acc[mt][nt][r] + bias[col];
            }
}

// ---------- fused flash attention + compressive memory read + gate ----------
// grid (48,16). bx<32: two-unit split (qt = 31-(bx>>1), unit = bx&1);
// bx>=32: single-unit qt = 15-(bx-32). 3 blocks/CU, register prefetch.
__global__ __launch_bounds__(256, 3) void flash_gate_k(
    const _Float16* __restrict__ Qh, const _Float16* __restrict__ Khg,
    const _Float16* __restrict__ Vtg, const _Float16* __restrict__ memT,
    const float* __restrict__ zp, const float* __restrict__ betas,
    _Float16* __restrict__ Cmb, _Float16* __restrict__ Opart,
    float* __restrict__ mpart, float* __restrict__ lpart) {
    __shared__ __align__(16) unsigned short Ksh[32 * 264];
    __shared__ __align__(16) unsigned short Vt[256 * 40];
    __shared__ __align__(16) unsigned short Pb[64 * 40];

    const int tid = threadIdx.x;
    const int lane = tid & 63;
    const int w = tid >> 6;
    const int quad = lane >> 4;
    const int l15 = lane & 15;
    const int bx = blockIdx.x;
    const int bh = blockIdx.y;
    const int b = bh >> 2, h = bh & 3;

    int qt, kt0, kt1, unit;
    if (bx < 32) {
        qt = 31 - (bx >> 1);
        unit = bx & 1;
        kt0 = unit ? (qt + 1) : 0;
        kt1 = unit ? (2 * qt + 2) : (qt + 1);
    } else {
        qt = 15 - (bx - 32);
        unit = 0;
        kt0 = 0;
        kt1 = 2 * qt + 2;
    }
    const bool two = (bx < 32);
    const int q0 = qt * 64;

    // ---- Q fragments (A-layout: m=lane&15, k=quad*8+j)
    const _Float16* Qrow = Qh + (size_t)(b * Sn + q0 + w * 16 + l15) * En + h * Dn;
    half8 qf[8];
    #pragma unroll
    for (int kc = 0; kc < 8; ++kc) qf[kc] = *(const half8*)(Qrow + kc * 32 + quad * 8);

    floatx4 acc[16];
    #pragma unroll
    for (int nt = 0; nt < 16; ++nt) acc[nt] = (floatx4){0.f, 0.f, 0.f, 0.f};

    const float gate = 1.0f / (1.0f + __expf(-betas[h]));
    const float omg = 1.0f - gate;
    _Float16* Cb = Cmb + (size_t)(b * Sn + q0 + w * 16) * En + h * Dn;
    _Float16* KshF = (_Float16*)Ksh;
    _Float16* VtF = (_Float16*)Vt;
    _Float16* PbF = (_Float16*)Pb;

    if (unit == 0) {
        // ---- A_mem = sigma_q @ mem (recompute sigma per chunk; den fused)
        float denp = 0.0f;
        const _Float16* memh = memT + (size_t)h * Dn * Dn;
        for (int dc = 0; dc < 8; ++dc) {
            __syncthreads();
            {
                const _Float16* src = memh + (size_t)tid * 256 + dc * 32;
                _Float16* dst = VtF + tid * 40;
                #pragma unroll
                for (int u = 0; u < 4; ++u) *(half8*)(dst + u * 8) = *(const half8*)(src + u * 8);
            }
            __syncthreads();
            half8 sv;
            const float* zb = zp + h * Dn + dc * 32 + quad * 8;
            #pragma unroll
            for (int j = 0; j < 8; ++j) {
                const float s = elup1((float)qf[dc][j]);
                sv[j] = (_Float16)s;
                denp += s * zb[j];
            }
            #pragma unroll
            for (int nt = 0; nt < 16; ++nt) {
                half8 bm = *(const half8*)(VtF + (nt * 16 + l15) * 40 + quad * 8);
                acc[nt] = MFMA16(sv, bm, acc[nt]);
            }
        }
        denp += __shfl_xor(denp, 16);
        denp += __shfl_xor(denp, 32);
        const float deninv = 1.0f / (denp + 1e-6f);
        float den4[4];
        #pragma unroll
        for (int r = 0; r < 4; ++r) den4[r] = __shfl(deninv, quad * 4 + r);
        #pragma unroll
        for (int nt = 0; nt < 16; ++nt)
            #pragma unroll
            for (int r = 0; r < 4; ++r) {
                Cb[(size_t)(quad * 4 + r) * En + nt * 16 + l15] =
                    (_Float16)(gate * acc[nt][r] * den4[r]);
                acc[nt][r] = 0.0f;
            }
    }

    // ---- causal flash loop over [kt0, kt1), K-tile = 32, reg prefetch
    const _Float16* Kbase = Khg + (size_t)(b * Sn) * En + h * Dn;
    const _Float16* Vtb = Vtg + (size_t)bh * 256 * (size_t)Sn;
    const _Float16* kptr = Kbase + (size_t)(kt0 * 32 + (tid >> 3)) * En + (tid & 7) * 32;
    const _Float16* vptr = Vtb + (size_t)tid * Sn + kt0 * 32;
    half8 kr[4], vr[4];
    #pragma unroll
    for (int u = 0; u < 4; ++u) {
        kr[u] = *(const half8*)(kptr + u * 8);
        vr[u] = *(const half8*)(vptr + u * 8);
    }

    float mold[4] = {-1e30f, -1e30f, -1e30f, -1e30f};
    float lsum[4] = {0.f, 0.f, 0.f, 0.f};
    float alpha[4];
    const int krow_off = (tid >> 3) * 264 + (tid & 7) * 32;

    for (int kt = kt0; kt < kt1; ++kt) {
        const int k0 = kt * 32;
        __syncthreads();   // all waves done reading Ksh/Vt from prev iter
        #pragma unroll
        for (int u = 0; u < 4; ++u) {
            *(half8*)(KshF + krow_off + u * 8) = kr[u];
            *(half8*)(VtF + tid * 40 + u * 8) = vr[u];
        }
        __syncthreads();
        if (kt + 1 < kt1) {  // prefetch next tile; in flight through compute
            kptr += 32 * En;
            vptr += 32;
            #pragma unroll
            for (int u = 0; u < 4; ++u) {
                kr[u] = *(const half8*)(kptr + u * 8);
                vr[u] = *(const half8*)(vptr + u * 8);
            }
        }

        floatx4 S0 = (floatx4){0.f, 0.f, 0.f, 0.f};
        floatx4 S1 = (floatx4){0.f, 0.f, 0.f, 0.f};
        #pragma unroll
        for (int kc = 0; kc < 8; ++kc) {
            half8 kf0 = *(const half8*)(KshF + l15 * 264 + kc * 32 + quad * 8);
            half8 kf1 = *(const half8*)(KshF + (16 + l15) * 264 + kc * 32 + quad * 8);
            S0 = MFMA16(qf[kc], kf0, S0);
            S1 = MFMA16(qf[kc], kf1, S1);
        }
        if (kt >= 2 * qt) {  // only diagonal tiles need the causal mask
            #pragma unroll
            for (int r = 0; r < 4; ++r) {
                const int qg = q0 + w * 16 + quad * 4 + r;
                if (k0 + l15 > qg) S0[r] = -1e30f;
                if (k0 + 16 + l15 > qg) S1[r] = -1e30f;
            }
        }
        #pragma unroll
        for (int r = 0; r < 4; ++r) {
            float mx = fmaxf(S0[r], S1[r]);
            mx = fmaxf(mx, __shfl_xor(mx, 1));
            mx = fmaxf(mx, __shfl_xor(mx, 2));
            mx = fmaxf(mx, __shfl_xor(mx, 4));
            mx = fmaxf(mx, __shfl_xor(mx, 8));
            const float mnew = fmaxf(mold[r], mx);
            alpha[r] = __expf(mold[r] - mnew);
            mold[r] = mnew;
            const float p0 = __expf(S0[r] - mnew);
            const float p1 = __expf(S1[r] - mnew);
            float ps = p0 + p1;
            ps += __shfl_xor(ps, 1);
            ps += __shfl_xor(ps, 2);
            ps += __shfl_xor(ps, 4);
            ps += __shfl_xor(ps, 8);
            lsum[r] = lsum[r] * alpha[r] + ps;
            _Float16* pr = PbF + (w * 16 + quad * 4 + r) * 40;
            pr[l15] = (_Float16)p0;
            pr[16 + l15] = (_Float16)p1;
        }
        #pragma unroll
        for (int nt = 0; nt < 16; ++nt) {
            acc[nt][0] *= alpha[0];
            acc[nt][1] *= alpha[1];
            acc[nt][2] *= alpha[2];
            acc[nt][3] *= alpha[3];
        }
        // P rows are wave-private: LDS fence only, no block barrier
        __asm__ volatile("s_waitcnt lgkmcnt(0)" ::: "memory");
        half8 pf = *(const half8*)(PbF + (w * 16 + l15) * 40 + quad * 8);
        #pragma unroll
        for (int nt = 0; nt < 16; ++nt) {
            half8 vf = *(const half8*)(VtF + (nt * 16 + l15) * 40 + quad * 8);
            acc[nt] = MFMA16(pf, vf, acc[nt]);
        }
    }

    if (!two) {
        // single unit: Cmb += (1-gate) * O / l
        #pragma unroll
        for (int r = 0; r < 4; ++r) alpha[r] = omg / lsum[r];
        #pragma unroll
        for (int nt = 0; nt < 16; ++nt)
            #pragma unroll
            for (int r = 0; r < 4; ++r) {
                const size_t idx = (size_t)(quad * 4 + r) * En + nt * 16 + l15;
                Cb[idx] = (_Float16)((float)Cb[idx] + acc[nt][r] * alpha[r]);
            }
    } else {
        // write unnormalized partial (O, m, l) for the merge kernel
        const int pidx = ((qt - 16) * 16 + bh) * 2 + unit;
        _Float16* Op = Opart + ((size_t)pidx * 64 + w * 16) * 256;
        #pragma unroll
        for (int nt = 0; nt < 16; ++nt)
            #pragma unroll
            for (int r = 0; r < 4; ++r)
                Op[(quad * 4 + r) * 256 + nt * 16 + l15] = (_Float16)acc[nt][r];
        if (l15 == 0) {
            #pragma unroll
            for (int r = 0; r < 4; ++r) {
                mpart[pidx * 64 + w * 16 + quad * 4 + r] = mold[r];
                lpart[pidx * 64 + w * 16 + quad * 4 + r] = lsum[r];
            }
        }
    }
}

// ---------- LSE-merge of the two split-K partials (qt >= 16) ----------------
__global__ __launch_bounds__(256) void merge_k(
    const _Float16* __restrict__ Opart, const float* __restrict__ mpart,
    const float* __restrict__ lpart, const float* __restrict__ betas,
    _Float16* __restrict__ Cmb) {
    const int qi = blockIdx.x;  // qt = 16 + qi
    const int bh = blockIdx.y;
    const int b = bh >> 2, h = bh & 3;
    const int tid = threadIdx.x;
    const int idx = (qi * 16 + bh) * 2;
    const float gate = 1.0f / (1.0f + __expf(-betas[h]));
    const float omg = 1.0f - gate;
    const int rsub = tid >> 6;
    const int c0 = (tid & 63) * 4;
    const _Float16* O0 = Opart + (size_t)idx * 64 * 256;
    const _Float16* O1 = O0 + 64 * 256;
    const int q0 = (16 + qi) * 64;
    for (int chunk = 0; chunk < 16; ++chunk) {
        const int r = chunk * 4 + rsub;
        const float m0 = mpart[idx * 64 + r], l0 = lpart[idx * 64 + r];
        const float m1 = mpart[(idx + 1) * 64 + r], l1 = lpart[(idx + 1) * 64 + r];
        const float mm = fmaxf(m0, m1);
        const float s0 = __expf(m0 - mm), s1 = __expf(m1 - mm);
        const float rl = omg / (l0 * s0 + l1 * s1);
        half4v o0 = *(const half4v*)(O0 + r * 256 + c0);
        half4v o1 = *(const half4v*)(O1 + r * 256 + c0);
        _Float16* cp = Cmb + (size_t)(b * Sn + q0 + r) * En + h * Dn + c0;
        half4v cv = *(half4v*)cp;
        #pragma unroll
        for (int j = 0; j < 4; ++j)
            cv[j] = (_Float16)((float)cv[j] + ((float)o0[j] * s0 + (float)o1[j] * s1) * rl);
        *(half4v*)cp = cv;
    }
}

// ---------- U = V - (sigma_k@mem)/(sigma_k.z+eps), in place on V (fp16) -----
__global__ __launch_bounds__(256) void delta_v_k(
    const _Float16* __restrict__ Kg, _Float16* __restrict__ Vg,
    const float* __restrict__ memp, const float* __restrict__ zp) {
    __shared__ float SK[32][256];
    __shared__ float rden[32];
    const int tid = threadIdx.x;
    const int st = blockIdx.x;
    const int h = blockIdx.y;
    const int b = blockIdx.z;
    const int s0 = st * 32;
    const _Float16* Kb = Kg + (size_t)(b * Sn + s0) * En + h * Dn;
    _Float16* Vb = Vg + (size_t)(b * Sn + s0) * En + h * Dn;
    const float* memh = memp + (size_t)h * Dn * Dn;
    const float* zh = zp + (size_t)h * Dn;

    {
        const int lr = tid >> 3, ld = (tid & 7) * 32;
        const _Float16* kr = Kb + (size_t)lr * En + ld;
        #pragma unroll
        for (int u = 0; u < 4; ++u) {
            half8 k8 = *(const half8*)(kr + u * 8);
            #pragma unroll
            for (int j = 0; j < 8; ++j) SK[lr][ld + u * 8 + j] = elup1((float)k8[j]);
        }
    }
    __syncthreads();
    {
        const int r = tid >> 3;
        const int sl = (tid & 7) << 5;
        float part = 0.0f;
        #pragma unroll 8
        for (int d = 0; d < 32; ++d) part += SK[r][sl + d] * zh[sl + d];
        part += __shfl_down(part, 4);
        part += __shfl_down(part, 2);
        part += __shfl_down(part, 1);
        if ((tid & 7) == 0) rden[r] = 1.0f / (part + 1e-6f);
    }
    __syncthreads();
    const int c0 = (tid & 63) << 2;
    const int rb = tid >> 6;
    float dl[8][4] = {};
    for (int kk = 0; kk < Dn; ++kk) {
        const float4 m4 = *(const float4*)(memh + (size_t)kk * Dn + c0);
        #pragma unroll
        for (int k = 0; k < 8; ++k) {
            const float sk = SK[rb + 4 * k][kk];
            dl[k][0] += sk * m4.x;
            dl[k][1] += sk * m4.y;
            dl[k][2] += sk * m4.z;
            dl[k][3] += sk * m4.w;
        }
    }
    #pragma unroll
    for (int k = 0; k < 8; ++k) {
        const int r = rb + 4 * k;
        const float rd = rden[r];
        _Float16* vp = Vb + (size_t)r * En + c0;
        half4v v4 = *(half4v*)vp;
        #pragma unroll
        for (int j = 0; j < 4; ++j) v4[j] = (_Float16)((float)v4[j] - dl[k][j] * rd);
        *(half4v*)vp = v4;
    }
}

// ---------- mem_new[b,h] = mem[h] + sigma_k^T @ U  (fp32 vector) ------------
__global__ __launch_bounds__(256) void mem_update_k(
    const _Float16* __restrict__ Kg, const _Float16* __restrict__ U,
    const float* __restrict__ memp, float* __restrict__ mem_new) {
    __shared__ float As[16][64];
    __shared__ float Bs[16][64];
    const int tid = threadIdx.x;
    const int bn = blockIdx.x * 64;
    const int bm = blockIdx.y * 64;
    const int bh = blockIdx.z;
    const int b = bh >> 2;
    const int h = bh & 3;
    const _Float16* Kb = Kg + (size_t)b * Sn * En + h * Dn;
    const _Float16* Ub = U + (size_t)b * Sn * En + h * Dn;
    const int tr = tid >> 4, tc = tid & 15;
    const int lr = tid >> 4;
    const int lc = (tid & 15) << 2;
    float acc[4][4] = {};
    for (int s0 = 0; s0 < Sn; s0 += 16) {
        half4v a4 = *(const half4v*)(Kb + (size_t)(s0 + lr) * En + bm + lc);
        As[lr][lc + 0] = elup1((float)a4[0]);
        As[lr][lc + 1] = elup1((float)a4[1]);
        As[lr][lc + 2] = elup1((float)a4[2]);
        As[lr][lc + 3] = elup1((float)a4[3]);
        half4v b4 = *(const half4v*)(Ub + (size_t)(s0 + lr) * En + bn + lc);
        Bs[lr][lc + 0] = (float)b4[0];
        Bs[lr][lc + 1] = (float)b4[1];
        Bs[lr][lc + 2] = (float)b4[2];
        Bs[lr][lc + 3] = (float)b4[3];
        __syncthreads();
        #pragma unroll
        for (int kk = 0; kk < 16; ++kk) {
            float a[4], bb[4];
            #pragma unroll
            for (int i = 0; i < 4; ++i) a[i] = As[kk][tr * 4 + i];
            #pragma unroll
            for (int j = 0; j < 4; ++j) bb[j] = Bs[kk][tc * 4 + j];
            #pragma unroll
            for (int i = 0; i < 4; ++i)
                #pragma unroll
                for (int j = 0; j < 4; ++j)
                    acc[i][j] += a[i] * bb[j];
        }
        __syncthreads();
    }
    const float* memh = memp + (size_t)h * Dn * Dn;
    float* mout = mem_new + (size_t)bh * Dn * Dn;
    #pragma unroll
    for (int i = 0; i < 4; ++i) {
        const int dm = bm + tr * 4 + i;
        const float4 m4 = *(const float4*)(memh + (size_t)dm * Dn + bn + tc * 4);
        float4 r;
        r.x = m4.x + acc[i][0];
        r.y = m4.y + acc[i][1];
        r.z = m4.z + acc[i][2];
        r.w = m4.w + acc[i][3];
        *(float4*)(mout + (size_t)dm * Dn + bn + tc * 4) = r;
    }
}

// ---------- z_new = z + sum_s sigma_k ---------------------------------------
__global__ __launch_bounds__(256) void znew_init_k(
    const float* __restrict__ zp, float* __restrict__ z_new) {
    const int bh = blockIdx.x;
    const int h = bh & 3;
    z_new[(size_t)bh * Dn + threadIdx.x] = zp[(size_t)h * Dn + threadIdx.x];
}

__global__ __launch_bounds__(256) void znew_acc_k(
    const _Float16* __restrict__ Kg, float* __restrict__ z_new) {
    const int bh = blockIdx.y;
    const int b = bh >> 2;
    const int h = bh & 3;
    const int s0 = blockIdx.x * 256;
    const _Float16* Kb = Kg + (size_t)(b * Sn + s0) * En + h * Dn;
    float acc = 0.0f;
    for (int s = 0; s < 256; ++s) acc += elup1((float)Kb[(size_t)s * En + threadIdx.x]);
    atomicAdd(&z_new[(size_t)bh * Dn + threadIdx.x], acc);
}

extern "C" void kernel_launch(void* const* d_in, const int* in_sizes, int n_in,
                              void* d_out, int out_size, void* d_ws, size_t ws_size,
                              hipStream_t stream) {
    const float* hidden = (const float*)d_in[0];
    const float* Wq = (const float*)d_in[1];
    const float* Wk = (const float*)d_in[2];
    const float* Wv = (const float*)d_in[3];
    const float* Wo = (const float*)d_in[4];
    const float* bo = (const float*)d_in[5];
    const float* betas = (const float*)d_in[6];
    const float* memp = (const float*)d_in[7];
    const float* zp = (const float*)d_in[8];

    float* out = (float*)d_out;                          // [B,S,E]
    float* mem_new = out + (size_t)Bn * Sn * En;         // [B,H,D,D]
    float* z_new = mem_new + (size_t)Bn * Hn * Dn * Dn;  // [B,H,D]

    const size_t BSE = (size_t)Bn * Sn * En;
    _Float16* p = (_Float16*)d_ws;
    _Float16* Qh = p;    p += BSE;
    _Float16* Kh = p;    p += BSE;
    _Float16* Vh = p;    p += BSE;
    _Float16* Vtg = p;   p += BSE;
    _Float16* Cmb = p;   p += BSE;
    _Float16* Opart = p; p += (size_t)512 * 64 * 256;    // = BSE
    _Float16* WqT = p;   p += (size_t)En * En;
    _Float16* WkT = p;   p += (size_t)En * En;
    _Float16* WvT = p;   p += (size_t)En * En;
    _Float16* WoT = p;   p += (size_t)En * En;
    _Float16* memT = p;  p += (size_t)Hn * Dn * Dn;
    float* fp = (float*)p;
    float* mpart = fp;   fp += 512 * 64;
    float* lpart = fp;   fp += 512 * 64;

    trans_f32f16_k<<<dim3(16, 16, 1), 256, 0, stream>>>(Wq, WqT, En, En);
    trans_f32f16_k<<<dim3(16, 16, 1), 256, 0, stream>>>(Wk, WkT, En, En);
    trans_f32f16_k<<<dim3(16, 16, 1), 256, 0, stream>>>(Wv, WvT, En, En);
    trans_f32f16_k<<<dim3(16, 16, 1), 256, 0, stream>>>(Wo, WoT, En, En);
    trans_f32f16_k<<<dim3(4, 4, 4), 256, 0, stream>>>(memp, memT, Dn, Dn);

    gemm16_k<true><<<dim3(8, 64), 256, 0, stream>>>(hidden, WqT, Qh, nullptr, nullptr);
    gemm16_k<true><<<dim3(8, 64), 256, 0, stream>>>(hidden, WkT, Kh, nullptr, nullptr);
    gemm16_k<true><<<dim3(8, 64), 256, 0, stream>>>(hidden, WvT, Vh, nullptr, nullptr);

    trans_h16_k<<<dim3(32, 16, 4), 256, 0, stream>>>(Vh, Vtg);

    flash_gate_k<<<dim3(48, 16), 256, 0, stream>>>(
        Qh, Kh, Vtg, memT, zp, betas, Cmb, Opart, mpart, lpart);
    merge_k<<<dim3(16, 16), 256, 0, stream>>>(Opart, mpart, lpart, betas, Cmb);

    delta_v_k<<<dim3(64, 4, 4), 256, 0, stream>>>(Kh, Vh, memp, zp);
    mem_update_k<<<dim3(4, 4, 16), 256, 0, stream>>>(Kh, Vh, memp, mem_new);

    znew_init_k<<<16, 256, 0, stream>>>(zp, z_new);
    znew_acc_k<<<dim3(8, 16), 256, 0, stream>>>(Kh, z_new);

    gemm16_k<false><<<dim3(8, 64), 256, 0, stream>>>(Cmb, WoT, nullptr, out, bo);
}